// Round 1
// baseline (257.334 us; speedup 1.0000x reference)
//
#include <hip/hip_runtime.h>
#include <stdint.h>

// RelationalNetwork: B=8, C=64, O=256, TE=128, GT=FP=256, A=32
// Decomposition:
//   U[b,i,d] = x_i . W1[0:66]  + (code.W1[132:260] + b1)   (bf16, ws)
//   V[b,j,d] = x_j . W1[66:132]                            (bf16, ws)
//   per tril tile (128 pairs): h1=relu(U_i+V_j) in LDS -> MFMA xW2^T -> relu
//     -> LDS -> MFMA xW3^T -> relu -> row-sum -> partial[b,tile,256]
//   tail: reduce partials + f_phi (fp32 scalar)

#define NPAIR 32896   // 256*257/2 = 257 tiles * 128 rows exactly
#define NTILE 257

using short8  = __attribute__((ext_vector_type(8))) short;
using float4v = __attribute__((ext_vector_type(4))) float;

__device__ __forceinline__ float asf(unsigned u) {
    union { unsigned u; float f; } c; c.u = u; return c.f;
}
__device__ __forceinline__ unsigned short f2bf(float f) {
    union { float f; unsigned u; } c; c.f = f;
    unsigned u = c.u;
    u += 0x7FFFu + ((u >> 16) & 1u);   // RNE
    return (unsigned short)(u >> 16);
}

// ---- pair index table: p -> (i,j), j<=i ---------------------------------
__global__ void k_idx(unsigned char* __restrict__ idx) {
    int p = blockIdx.x * 256 + threadIdx.x;
    if (p >= NPAIR) return;
    float s = sqrtf(8.0f * (float)p + 1.0f);
    int i = (int)((s - 1.0f) * 0.5f);
    while ((i + 1) * (i + 2) / 2 <= p) ++i;
    while (i * (i + 1) / 2 > p) --i;
    int j = p - i * (i + 1) / 2;
    idx[2 * p]     = (unsigned char)i;
    idx[2 * p + 1] = (unsigned char)j;
}

// ---- Q[b,d] = code . W1[132:260] + b1 -----------------------------------
__global__ void k_qb(const float* __restrict__ code, const float* __restrict__ w1,
                     const float* __restrict__ b1, float* __restrict__ qb) {
    int b = blockIdx.x, d = threadIdx.x;
    float s = b1[d];
    const float* w = w1 + 132 * 256 + d;
    const float* c = code + b * 128;
    #pragma unroll 4
    for (int t = 0; t < 128; ++t) s += c[t] * w[t * 256];
    qb[b * 256 + d] = s;
}

// ---- transpose + cast gt_w2/gt_w3 to bf16 (W^T[n][k]) -------------------
__global__ void k_wt(const float* __restrict__ w2, const float* __restrict__ w3,
                     unsigned short* __restrict__ w2t, unsigned short* __restrict__ w3t) {
    __shared__ float t[64][65];
    const float* src = blockIdx.z ? w3 : w2;
    unsigned short* dst = blockIdx.z ? w3t : w2t;
    int k0 = blockIdx.x * 64, n0 = blockIdx.y * 64;
    int tx = threadIdx.x & 63, ty = threadIdx.x >> 6;
    #pragma unroll
    for (int r = ty; r < 64; r += 4)
        t[r][tx] = src[(k0 + r) * 256 + n0 + tx];
    __syncthreads();
    #pragma unroll
    for (int r = ty; r < 64; r += 4)
        dst[(n0 + r) * 256 + k0 + tx] = f2bf(t[tx][r]);
}

// ---- U,V precompute (bf16), Q+bias folded into U ------------------------
__global__ void k_uv(const float* __restrict__ x, const float* __restrict__ w1,
                     const float* __restrict__ qb,
                     unsigned short* __restrict__ ub, unsigned short* __restrict__ vb) {
    int i = blockIdx.x, b = blockIdx.y, d = threadIdx.x;
    float su = qb[b * 256 + d];
    float sv = 0.f;
    const float* xp = x + (b * 64) * 256 + i;
    #pragma unroll 4
    for (int c = 0; c < 64; ++c) {
        float xv = xp[c * 256];
        su += xv * w1[c * 256 + d];
        sv += xv * w1[(66 + c) * 256 + d];
    }
    float yy = (float)(i >> 4) * (2.0f / 15.0f) - 1.0f;
    float xx = (float)(i & 15) * (2.0f / 15.0f) - 1.0f;
    su += yy * w1[64 * 256 + d] + xx * w1[65 * 256 + d];
    sv += yy * w1[130 * 256 + d] + xx * w1[131 * 256 + d];
    ub[(b * 256 + i) * 256 + d] = f2bf(su);
    vb[(b * 256 + i) * 256 + d] = f2bf(sv);
}

// ---- fused g_theta L2+L3 + tril row-sum ---------------------------------
// LDS tile 128x256 bf16 (=64KiB exactly -> 2 wg/CU). XOR chunk swizzle:
// element (r,d) stored at r*256 + (((d>>3) ^ (r&7))<<3 | (d&7)) so the
// 16-lane A-frag ds_read_b128 column spreads across all banks (2-way, free).
__global__ __launch_bounds__(256, 2) void k_main(
    const unsigned short* __restrict__ ub, const unsigned short* __restrict__ vb,
    const unsigned short* __restrict__ w2t, const unsigned short* __restrict__ w3t,
    const unsigned char* __restrict__ idx,
    const float* __restrict__ b2, const float* __restrict__ b3,
    float* __restrict__ part)
{
    __shared__ unsigned short tile[128 * 256];
    const int tid  = threadIdx.x;
    const int b    = blockIdx.y, tIdx = blockIdx.x;
    const int lane = tid & 63;
    const int wave = tid >> 6;
    const int n0   = wave * 64;            // wave's 64-column slice
    const int lm   = lane & 15, quad = lane >> 4;

    // ---- build h1 = relu(U_i + V_j) into LDS ----
    {
        const int r = tid >> 1, half = tid & 1;
        const int p = tIdx * 128 + r;
        const int i = idx[2 * p], j = idx[2 * p + 1];
        const unsigned short* up = ub + ((b * 256 + i) * 256) + half * 128;
        const unsigned short* vp = vb + ((b * 256 + j) * 256) + half * 128;
        const int s = r & 7;
        #pragma unroll
        for (int it = 0; it < 16; ++it) {
            uint4 uu = *(const uint4*)(up + it * 8);
            uint4 vv = *(const uint4*)(vp + it * 8);
            unsigned ua[4] = {uu.x, uu.y, uu.z, uu.w};
            unsigned va[4] = {vv.x, vv.y, vv.z, vv.w};
            unsigned ra[4];
            #pragma unroll
            for (int q = 0; q < 4; ++q) {
                float lo = asf(ua[q] << 16) + asf(va[q] << 16);
                float hi = asf(ua[q] & 0xFFFF0000u) + asf(va[q] & 0xFFFF0000u);
                lo = fmaxf(lo, 0.f); hi = fmaxf(hi, 0.f);
                ra[q] = (unsigned)f2bf(lo) | ((unsigned)f2bf(hi) << 16);
            }
            const int chunk = half * 16 + it;
            uint4 r4; r4.x = ra[0]; r4.y = ra[1]; r4.z = ra[2]; r4.w = ra[3];
            *(uint4*)(&tile[r * 256 + ((chunk ^ s) << 3)]) = r4;
        }
    }
    __syncthreads();

    float b2c[4], b3c[4];
    #pragma unroll
    for (int nt = 0; nt < 4; ++nt) {
        b2c[nt] = b2[n0 + nt * 16 + lm];
        b3c[nt] = b3[n0 + nt * 16 + lm];
    }

    const float4v zero4 = {0.f, 0.f, 0.f, 0.f};
    float4v acc[8][4];
    #pragma unroll
    for (int mt = 0; mt < 8; ++mt)
        #pragma unroll
        for (int nt = 0; nt < 4; ++nt) acc[mt][nt] = zero4;

    // ---- GEMM1: h2 = h1 @ W2 ----
    const unsigned short* bbase2 = w2t + (n0 + lm) * 256 + quad * 8;
    for (int ks = 0; ks < 8; ++ks) {
        short8 bfr[4];
        #pragma unroll
        for (int nt = 0; nt < 4; ++nt)
            bfr[nt] = *(const short8*)(bbase2 + nt * 4096 + ks * 32);
        const int coff = (((ks * 4 + quad) ^ (lane & 7)) << 3);
        short8 afr[8];
        #pragma unroll
        for (int mt = 0; mt < 8; ++mt)
            afr[mt] = *(const short8*)(&tile[(mt * 16 + lm) * 256 + coff]);
        #pragma unroll
        for (int mt = 0; mt < 8; ++mt)
            #pragma unroll
            for (int nt = 0; nt < 4; ++nt)
                acc[mt][nt] = __builtin_amdgcn_mfma_f32_16x16x32_bf16(
                    afr[mt], bfr[nt], acc[mt][nt], 0, 0, 0);
    }
    __syncthreads();

    // ---- h2 = relu(acc + b2) back to LDS (bf16, swizzled) ----
    #pragma unroll
    for (int mt = 0; mt < 8; ++mt) {
        #pragma unroll
        for (int nt = 0; nt < 4; ++nt) {
            const int col = n0 + nt * 16 + lm;
            #pragma unroll
            for (int rg = 0; rg < 4; ++rg) {
                const int row = mt * 16 + quad * 4 + rg;
                float v = fmaxf(acc[mt][nt][rg] + b2c[nt], 0.f);
                tile[row * 256 + ((((col >> 3) ^ (row & 7)) << 3) | (col & 7))] = f2bf(v);
            }
        }
    }
    __syncthreads();

    // ---- GEMM2: rel = h2 @ W3 ----
    #pragma unroll
    for (int mt = 0; mt < 8; ++mt)
        #pragma unroll
        for (int nt = 0; nt < 4; ++nt) acc[mt][nt] = zero4;

    const unsigned short* bbase3 = w3t + (n0 + lm) * 256 + quad * 8;
    for (int ks = 0; ks < 8; ++ks) {
        short8 bfr[4];
        #pragma unroll
        for (int nt = 0; nt < 4; ++nt)
            bfr[nt] = *(const short8*)(bbase3 + nt * 4096 + ks * 32);
        const int coff = (((ks * 4 + quad) ^ (lane & 7)) << 3);
        short8 afr[8];
        #pragma unroll
        for (int mt = 0; mt < 8; ++mt)
            afr[mt] = *(const short8*)(&tile[(mt * 16 + lm) * 256 + coff]);
        #pragma unroll
        for (int mt = 0; mt < 8; ++mt)
            #pragma unroll
            for (int nt = 0; nt < 4; ++nt)
                acc[mt][nt] = __builtin_amdgcn_mfma_f32_16x16x32_bf16(
                    afr[mt], bfr[nt], acc[mt][nt], 0, 0, 0);
    }

    // ---- relu + row-sum over the 128 pairs of this tile ----
    #pragma unroll
    for (int nt = 0; nt < 4; ++nt) {
        float s = 0.f;
        #pragma unroll
        for (int mt = 0; mt < 8; ++mt)
            #pragma unroll
            for (int rg = 0; rg < 4; ++rg)
                s += fmaxf(acc[mt][nt][rg] + b3c[nt], 0.f);
        s += __shfl_xor(s, 16);
        s += __shfl_xor(s, 32);
        if (quad == 0)
            part[((size_t)(b * NTILE + tIdx)) * 256 + n0 + nt * 16 + lm] = s;
    }
}

// ---- reduce partials + f_phi (fp32) -------------------------------------
__global__ void k_tail(const float* __restrict__ part,
                       const float* __restrict__ fw1, const float* __restrict__ fb1,
                       const float* __restrict__ fw2, const float* __restrict__ fb2,
                       const float* __restrict__ fw3, const float* __restrict__ fb3,
                       float* __restrict__ out) {
    __shared__ float s0[256], s1[256];
    const int b = blockIdx.x, d = threadIdx.x;
    float s = 0.f;
    const float* pp = part + (size_t)b * NTILE * 256 + d;
    for (int t = 0; t < NTILE; ++t) s += pp[t * 256];
    s0[d] = s;
    __syncthreads();
    float a1 = fb1[d];
    for (int k = 0; k < 256; ++k) a1 += s0[k] * fw1[k * 256 + d];
    s1[d] = fmaxf(a1, 0.f);
    __syncthreads();
    float a2 = fb2[d];
    for (int k = 0; k < 256; ++k) a2 += s1[k] * fw2[k * 256 + d];
    s0[d] = fmaxf(a2, 0.f);          // safe: all s0 reads finished before barrier2
    __syncthreads();
    if (d < 32) {
        float o = fb3[d];
        for (int k = 0; k < 256; ++k) o += s0[k] * fw3[k * 32 + d];
        out[b * 32 + d] = o;
    }
}

extern "C" void kernel_launch(void* const* d_in, const int* in_sizes, int n_in,
                              void* d_out, int out_size, void* d_ws, size_t ws_size,
                              hipStream_t stream) {
    const float* x    = (const float*)d_in[0];
    const float* code = (const float*)d_in[1];
    const float* gw1  = (const float*)d_in[2];
    const float* gb1  = (const float*)d_in[3];
    const float* gw2  = (const float*)d_in[4];
    const float* gb2  = (const float*)d_in[5];
    const float* gw3  = (const float*)d_in[6];
    const float* gb3  = (const float*)d_in[7];
    const float* fw1  = (const float*)d_in[8];
    const float* fb1  = (const float*)d_in[9];
    const float* fw2  = (const float*)d_in[10];
    const float* fb2  = (const float*)d_in[11];
    const float* fw3  = (const float*)d_in[12];
    const float* fb3  = (const float*)d_in[13];
    float* out = (float*)d_out;

    // workspace layout (bytes), total ~4.4 MB
    char* ws = (char*)d_ws;
    unsigned short* ub  = (unsigned short*)(ws);               // 1 MiB
    unsigned short* vb  = (unsigned short*)(ws + 1048576);     // 1 MiB
    unsigned short* w2t = (unsigned short*)(ws + 2097152);     // 128 KiB
    unsigned short* w3t = (unsigned short*)(ws + 2228224);     // 128 KiB
    unsigned char*  idx = (unsigned char*)(ws + 2359296);      // 64.25 KiB
    float* qb   = (float*)(ws + 2425088);                      // 8 KiB
    float* part = (float*)(ws + 2433280);                      // 2.0 MiB

    hipLaunchKernelGGL(k_idx, dim3(129), dim3(256), 0, stream, idx);
    hipLaunchKernelGGL(k_qb,  dim3(8),   dim3(256), 0, stream, code, gw1, gb1, qb);
    hipLaunchKernelGGL(k_wt,  dim3(4, 4, 2), dim3(256), 0, stream, gw2, gw3, w2t, w3t);
    hipLaunchKernelGGL(k_uv,  dim3(256, 8),  dim3(256), 0, stream, x, gw1, qb, ub, vb);
    hipLaunchKernelGGL(k_main, dim3(NTILE, 8), dim3(256), 0, stream,
                       ub, vb, w2t, w3t, idx, gb2, gb3, part);
    hipLaunchKernelGGL(k_tail, dim3(8), dim3(256), 0, stream,
                       part, fw1, fb1, fw2, fb2, fw3, fb3, out);
}